// Round 2
// baseline (294.794 us; speedup 1.0000x reference)
//
#include <hip/hip_runtime.h>
#include <hip/hip_bf16.h>

// Problem constants
#define B_ 2
#define N_ 48
#define H_ 256
#define NH_ 8
#define DH_ 32
#define KB_ 4  // k-slices per main block

typedef __attribute__((ext_vector_type(8))) short bf16x8;
typedef __attribute__((ext_vector_type(4))) float f32x4;

__device__ __forceinline__ unsigned short f2bf(float f) {
  unsigned u = __float_as_uint(f);
  u += 0x7FFFu + ((u >> 16) & 1u);
  return (unsigned short)(u >> 16);
}

// ---------------------------------------------------------------------------
// P0: pack [Wq|Wk|Wv] (256x768) and [Wsq|Wsk|Wsv] (256x96) into bf16 MFMA
// B-fragment order: frag[nt][kt][lane][i] = W[kt*32 + (lane>>4)*8 + i][nt*16 + (lane&15)]
// plus biascat768 = [bq|bk|bv].
// ---------------------------------------------------------------------------
__global__ void pack_kernel(const float* __restrict__ Wq, const float* __restrict__ Wk,
                            const float* __restrict__ Wv, const float* __restrict__ bq,
                            const float* __restrict__ bk, const float* __restrict__ bv,
                            const float* __restrict__ Wsq, const float* __restrict__ Wsk,
                            const float* __restrict__ Wsv,
                            unsigned short* __restrict__ wfrag_pair,
                            unsigned short* __restrict__ wfrag_main,
                            float* __restrict__ biascat) {
  int t = blockIdx.x * 256 + threadIdx.x;
  if (t < 196608) {  // 48 ntiles * 8 ktiles * 64 lanes * 8
    int i8 = t & 7, lane = (t >> 3) & 63, kt = (t >> 9) & 7, nt = t >> 12;
    int k = kt * 32 + ((lane >> 4) << 3) + i8;
    int n = nt * 16 + (lane & 15);
    const float* W = (n < 256) ? Wq : (n < 512) ? Wk : Wv;
    wfrag_pair[t] = f2bf(W[k * 256 + (n & 255)]);
  } else if (t < 196608 + 24576) {  // 6 ntiles * 8 * 64 * 8
    int p = t - 196608;
    int i8 = p & 7, lane = (p >> 3) & 63, kt = (p >> 9) & 7, nt = p >> 12;
    int k = kt * 32 + ((lane >> 4) << 3) + i8;
    int n = nt * 16 + (lane & 15);  // 0..95
    const float* W = (n < 32) ? Wsq : (n < 64) ? Wsk : Wsv;
    wfrag_main[p] = f2bf(W[k * 32 + (n & 31)]);
  } else if (t < 196608 + 24576 + 768) {
    int p = t - 196608 - 24576;
    const float* bsrc = (p < 256) ? bq : (p < 512) ? bk : bv;
    biascat[p] = bsrc[p & 255];
  }
}

// ---------------------------------------------------------------------------
// Shared helpers. LDS tile layout: bf16, row<<9 + col*2, XOR-swizzled by
// (row&7)<<4 (applied on both write and read sides).
// ---------------------------------------------------------------------------
__device__ __forceinline__ void gemm48xK(const char* tAc, const bf16x8* wf, f32x4 acc[3], int lane) {
#pragma unroll
  for (int kt = 0; kt < 8; ++kt) {
#pragma unroll
    for (int mt = 0; mt < 3; ++mt) {
      int row = mt * 16 + (lane & 15);
      int off = (row << 9) + (kt << 6) + ((lane >> 4) << 4);
      off ^= (row & 7) << 4;
      bf16x8 a = *reinterpret_cast<const bf16x8*>(tAc + off);
      acc[mt] = __builtin_amdgcn_mfma_f32_16x16x32_bf16(a, wf[kt], acc[mt], 0, 0, 0);
    }
  }
}

__device__ __forceinline__ void cvt_store(char* tAc, int tid, const float4 pf[8]) {
#pragma unroll
  for (int it = 0; it < 4; ++it) {
    int c = it * 384 + tid;
    int row = c >> 5;
    int off = (row << 9) + ((c & 31) << 4);
    off ^= (row & 7) << 4;
    float4 x = pf[it * 2], y = pf[it * 2 + 1];
    union { unsigned short us[8]; bf16x8 v; } o;
    o.us[0] = f2bf(x.x); o.us[1] = f2bf(x.y); o.us[2] = f2bf(x.z); o.us[3] = f2bf(x.w);
    o.us[4] = f2bf(y.x); o.us[5] = f2bf(y.y); o.us[6] = f2bf(y.z); o.us[7] = f2bf(y.w);
    *reinterpret_cast<bf16x8*>(tAc + off) = o.v;
  }
}

// ---------------------------------------------------------------------------
// A: pair projections.  proj[(b*48+i)*48+j][0:256]=q, [256:512]=k, [512:768]=v
// ---------------------------------------------------------------------------
__global__ __launch_bounds__(384, 3)
void pair_proj_kernel(const float* __restrict__ pair,
                      const unsigned short* __restrict__ wfrag_pair,
                      const float* __restrict__ biascat, float* __restrict__ proj) {
  __shared__ __align__(16) char tAc[48 * 256 * 2];
  int tid = threadIdx.x;
  int lane = tid & 63;
  int wave = tid >> 6;
  int gm = blockIdx.x >> 3;  // (b,i) group: 48 rows
  int gn = blockIdx.x & 7;   // 96-col group

  {
    float4 pf[8];
    const float4* src = reinterpret_cast<const float4*>(pair + (size_t)gm * 12288);
#pragma unroll
    for (int it = 0; it < 4; ++it) {
      int c = it * 384 + tid;
      pf[it * 2] = src[c * 2];
      pf[it * 2 + 1] = src[c * 2 + 1];
    }
    cvt_store(tAc, tid, pf);
  }

  bf16x8 wf[8];
  {
    const bf16x8* wp = reinterpret_cast<const bf16x8*>(wfrag_pair);
#pragma unroll
    for (int kt = 0; kt < 8; ++kt) wf[kt] = wp[((gn * 6 + wave) * 8 + kt) * 64 + lane];
  }
  __syncthreads();

  f32x4 acc[3];
#pragma unroll
  for (int mt = 0; mt < 3; ++mt) acc[mt] = (f32x4){0.f, 0.f, 0.f, 0.f};
  gemm48xK(tAc, wf, acc, lane);

  int col = gn * 96 + wave * 16 + (lane & 15);
  float bias = biascat[col];
  int jb = (lane >> 4) * 4;
#pragma unroll
  for (int mt = 0; mt < 3; ++mt) {
#pragma unroll
    for (int rr = 0; rr < 4; ++rr) {
      int j = mt * 16 + jb + rr;
      proj[(size_t)(gm * 48 + j) * 768 + col] = acc[mt][rr] + bias;
    }
  }
}

// ---------------------------------------------------------------------------
// Main: one block per (b,i, 4 consecutive k).  Software-pipelined: the next
// k-slice's 48x256 f32 tile is prefetched into registers while the current
// slice runs GEMM -> scores -> softmax -> PV.
// grid = 1152: bid -> xcd = bid&7, idx = bid>>3; g = xcd*12 + idx/12 (12
// same-(b,i) blocks land consecutively on one XCD for q/v L2 reuse).
// ---------------------------------------------------------------------------
__global__ __launch_bounds__(384, 4)
void e2e_main(const float* __restrict__ mask, const float* __restrict__ trip,
              const float* __restrict__ proj, const unsigned short* __restrict__ wfragm,
              const float* __restrict__ bsq, const float* __restrict__ bsk,
              const float* __restrict__ bsv, float* __restrict__ out) {
  __shared__ __align__(16) char tAc[48 * 256 * 2];  // 24576 B
  __shared__ float sqT[96][49];                     // [n][j], n: 0-31 sq, 32-63 sk, 64-95 sv
  __shared__ float khl[256];
  __shared__ float maskl[48];
  __shared__ float pbuf[8][48];

  int tid = threadIdx.x;
  int lane = tid & 63;
  int wave = tid >> 6;

  int bid = blockIdx.x;
  int xcd = bid & 7;
  int idx = bid >> 3;          // 0..143
  int g = xcd * 12 + idx / 12; // (b*48+i), 0..95
  int kg = idx % 12;
  int k0 = kg * KB_;
  int b = g / 48;
  int rowbase = g * 48;        // proj row of (b,i,j=0)

  // weight fragments (held across all 4 k-slices)
  bf16x8 wf[8];
  {
    const bf16x8* wp = reinterpret_cast<const bf16x8*>(wfragm);
#pragma unroll
    for (int kt = 0; kt < 8; ++kt) wf[kt] = wp[(wave * 8 + kt) * 64 + lane];
  }
  float biasn;
  {
    int n = wave * 16 + (lane & 15);
    const float* bp = (n < 32) ? bsq : (n < 64) ? bsk : bsv;
    biasn = bp[n & 31];
  }

  // prologue: prefetch first k-tile into registers
  float4 pf[8];
  {
    const float4* src = reinterpret_cast<const float4*>(trip + (size_t)(rowbase + k0) * 12288);
#pragma unroll
    for (int it = 0; it < 4; ++it) {
      int c = it * 384 + tid;
      pf[it * 2] = src[c * 2];
      pf[it * 2 + 1] = src[c * 2 + 1];
    }
  }

  for (int kk = 0; kk < KB_; ++kk) {
    int k = k0 + kk;
    int wg = rowbase + k;

    // stage current tile regs -> LDS (bf16, swizzled)
    cvt_store(tAc, tid, pf);

    // prefetch next k-tile (in flight across the whole compute chain below)
    if (kk + 1 < KB_) {
      const float4* src = reinterpret_cast<const float4*>(trip + (size_t)(wg + 1) * 12288);
#pragma unroll
      for (int it = 0; it < 4; ++it) {
        int c = it * 384 + tid;
        pf[it * 2] = src[c * 2];
        pf[it * 2 + 1] = src[c * 2 + 1];
      }
    }

    // per-k small loads
    if (tid < 256) khl[tid] = proj[(size_t)wg * 768 + 256 + tid];
    if (tid >= 256 && tid < 304) maskl[tid - 256] = mask[(b * 48 + k) * 48 + (tid - 256)];
    __syncthreads();

    // GEMM: sq|sk|sv = tile @ [Wsq|Wsk|Wsv]
    f32x4 acc[3];
#pragma unroll
    for (int mt = 0; mt < 3; ++mt) acc[mt] = (f32x4){0.f, 0.f, 0.f, 0.f};
    gemm48xK(tAc, wf, acc, lane);

    // epilogue: sqT[n][j] = acc + bias  (wave w owns n = w*16 .. w*16+15)
    {
      int n = wave * 16 + (lane & 15);
      int jb = (lane >> 4) * 4;
#pragma unroll
      for (int mt = 0; mt < 3; ++mt) {
#pragma unroll
        for (int rr = 0; rr < 4; ++rr) sqT[n][mt * 16 + jb + rr] = acc[mt][rr] + biasn;
      }
    }
    __syncthreads();

    // scores: 384 threads = 8h x 48j, f32
    {
      int j = tid % 48;
      int h = tid / 48;
      const float4* q4 = reinterpret_cast<const float4*>(proj + (size_t)(rowbase + j) * 768 + h * 32);
      float s = 0.f;
#pragma unroll
      for (int d4 = 0; d4 < 8; ++d4) {
        float4 q = q4[d4];
        int d = d4 * 4;
        s += (q.x + sqT[d + 0][j]) * (khl[h * 32 + d + 0] + sqT[32 + d + 0][j]);
        s += (q.y + sqT[d + 1][j]) * (khl[h * 32 + d + 1] + sqT[32 + d + 1][j]);
        s += (q.z + sqT[d + 2][j]) * (khl[h * 32 + d + 2] + sqT[32 + d + 2][j]);
        s += (q.w + sqT[d + 3][j]) * (khl[h * 32 + d + 3] + sqT[32 + d + 3][j]);
      }
      pbuf[h][j] = s * 0.17677669529663687f + maskl[j];  // 1/sqrt(32)
    }
    __syncthreads();

    // softmax over j per (h): waves 0..5 take rows wave, wave+6
    for (int h = wave; h < 8; h += 6) {
      float x = (lane < 48) ? pbuf[h][lane] : -INFINITY;
      float m = x;
#pragma unroll
      for (int off = 32; off; off >>= 1) m = fmaxf(m, __shfl_xor(m, off));
      float e = (lane < 48) ? __expf(x - m) : 0.f;
      float sum = e;
#pragma unroll
      for (int off = 32; off; off >>= 1) sum += __shfl_xor(sum, off);
      if (lane < 48) pbuf[h][lane] = e / sum;
    }
    __syncthreads();

    // PV: 256 threads = (h,d); v = proj_v[b,i,j, h*32+d] + sv[j][d]
    if (tid < 256) {
      int h = tid >> 5, d = tid & 31;
      const float* vbase = proj + (size_t)rowbase * 768 + 512 + tid;
      float a = 0.f;
#pragma unroll 8
      for (int j = 0; j < 48; ++j) a += pbuf[h][j] * (vbase[(size_t)j * 768] + sqT[64 + d][j]);
      out[(size_t)wg * 256 + tid] = a;
    }
    __syncthreads();  // protect sqT/pbuf/tAc before next k-slice
  }
}

// ---------------------------------------------------------------------------
extern "C" void kernel_launch(void* const* d_in, const int* in_sizes, int n_in,
                              void* d_out, int out_size, void* d_ws, size_t ws_size,
                              hipStream_t stream) {
  const float* mask = (const float*)d_in[0];
  const float* pair = (const float*)d_in[1];
  const float* trip = (const float*)d_in[2];
  const float* Wq = (const float*)d_in[3];
  const float* bq = (const float*)d_in[4];
  const float* Wk = (const float*)d_in[5];
  const float* bk = (const float*)d_in[6];
  const float* Wv = (const float*)d_in[7];
  const float* bv = (const float*)d_in[8];
  const float* Wsq = (const float*)d_in[9];
  const float* bsq = (const float*)d_in[10];
  const float* Wsk = (const float*)d_in[11];
  const float* bsk = (const float*)d_in[12];
  const float* Wsv = (const float*)d_in[13];
  const float* bsv = (const float*)d_in[14];

  char* ws = (char*)d_ws;
  float* proj = (float*)ws;                                               // 14,155,776 B
  unsigned short* wfrag_pair = (unsigned short*)(ws + 14155776);          // 393,216 B
  unsigned short* wfrag_main = (unsigned short*)(ws + 14155776 + 393216); // 49,152 B
  float* biascat = (float*)(ws + 14155776 + 393216 + 49152);              // 3,072 B

  pack_kernel<<<867, 256, 0, stream>>>(Wq, Wk, Wv, bq, bk, bv, Wsq, Wsk, Wsv,
                                       wfrag_pair, wfrag_main, biascat);
  pair_proj_kernel<<<768, 384, 0, stream>>>(pair, wfrag_pair, biascat, proj);
  e2e_main<<<1152, 384, 0, stream>>>(mask, trip, proj, wfrag_main, bsq, bsk, bsv,
                                     (float*)d_out);
}

// Round 3
// 133.123 us; speedup vs baseline: 2.2145x; 2.2145x over previous
//
#include <hip/hip_runtime.h>
#include <hip/hip_bf16.h>

// Problem constants
#define B_ 2
#define N_ 48
#define H_ 256
#define NH_ 8
#define DH_ 32
#define KB_ 4  // k-slices per main block

typedef __attribute__((ext_vector_type(8))) short bf16x8;
typedef __attribute__((ext_vector_type(4))) float f32x4;

__device__ __forceinline__ unsigned short f2bf(float f) {
  unsigned u = __float_as_uint(f);
  u += 0x7FFFu + ((u >> 16) & 1u);
  return (unsigned short)(u >> 16);
}

// ---------------------------------------------------------------------------
// P0: pack [Wq|Wk|Wv] (256x768) and [Wsq|Wsk|Wsv] (256x96) into bf16 MFMA
// B-fragment order: frag[nt][kt][lane][i] = W[kt*32 + (lane>>4)*8 + i][nt*16 + (lane&15)]
// plus biascat768 = [bq|bk|bv].
// ---------------------------------------------------------------------------
__global__ void pack_kernel(const float* __restrict__ Wq, const float* __restrict__ Wk,
                            const float* __restrict__ Wv, const float* __restrict__ bq,
                            const float* __restrict__ bk, const float* __restrict__ bv,
                            const float* __restrict__ Wsq, const float* __restrict__ Wsk,
                            const float* __restrict__ Wsv,
                            unsigned short* __restrict__ wfrag_pair,
                            unsigned short* __restrict__ wfrag_main,
                            float* __restrict__ biascat) {
  int t = blockIdx.x * 256 + threadIdx.x;
  if (t < 196608) {  // 48 ntiles * 8 ktiles * 64 lanes * 8
    int i8 = t & 7, lane = (t >> 3) & 63, kt = (t >> 9) & 7, nt = t >> 12;
    int k = kt * 32 + ((lane >> 4) << 3) + i8;
    int n = nt * 16 + (lane & 15);
    const float* W = (n < 256) ? Wq : (n < 512) ? Wk : Wv;
    wfrag_pair[t] = f2bf(W[k * 256 + (n & 255)]);
  } else if (t < 196608 + 24576) {  // 6 ntiles * 8 * 64 * 8
    int p = t - 196608;
    int i8 = p & 7, lane = (p >> 3) & 63, kt = (p >> 9) & 7, nt = p >> 12;
    int k = kt * 32 + ((lane >> 4) << 3) + i8;
    int n = nt * 16 + (lane & 15);  // 0..95
    const float* W = (n < 32) ? Wsq : (n < 64) ? Wsk : Wsv;
    wfrag_main[p] = f2bf(W[k * 32 + (n & 31)]);
  } else if (t < 196608 + 24576 + 768) {
    int p = t - 196608 - 24576;
    const float* bsrc = (p < 256) ? bq : (p < 512) ? bk : bv;
    biascat[p] = bsrc[p & 255];
  }
}

// ---------------------------------------------------------------------------
// Shared helpers. LDS tile layout: bf16, row<<9 + col*2, XOR-swizzled by
// (row&7)<<4 (applied on both write and read sides).
// ---------------------------------------------------------------------------
__device__ __forceinline__ void gemm48xK(const char* tAc, const bf16x8* wf, f32x4 acc[3], int lane) {
#pragma unroll
  for (int kt = 0; kt < 8; ++kt) {
#pragma unroll
    for (int mt = 0; mt < 3; ++mt) {
      int row = mt * 16 + (lane & 15);
      int off = (row << 9) + (kt << 6) + ((lane >> 4) << 4);
      off ^= (row & 7) << 4;
      bf16x8 a = *reinterpret_cast<const bf16x8*>(tAc + off);
      acc[mt] = __builtin_amdgcn_mfma_f32_16x16x32_bf16(a, wf[kt], acc[mt], 0, 0, 0);
    }
  }
}

__device__ __forceinline__ void cvt_store(char* tAc, int tid, const float4 pf[8]) {
#pragma unroll
  for (int it = 0; it < 4; ++it) {
    int c = it * 384 + tid;
    int row = c >> 5;
    int off = (row << 9) + ((c & 31) << 4);
    off ^= (row & 7) << 4;
    float4 x = pf[it * 2], y = pf[it * 2 + 1];
    union { unsigned short us[8]; bf16x8 v; } o;
    o.us[0] = f2bf(x.x); o.us[1] = f2bf(x.y); o.us[2] = f2bf(x.z); o.us[3] = f2bf(x.w);
    o.us[4] = f2bf(y.x); o.us[5] = f2bf(y.y); o.us[6] = f2bf(y.z); o.us[7] = f2bf(y.w);
    *reinterpret_cast<bf16x8*>(tAc + off) = o.v;
  }
}

// ---------------------------------------------------------------------------
// A: pair projections.  proj[(b*48+i)*48+j][0:256]=q, [256:512]=k, [512:768]=v
// ---------------------------------------------------------------------------
__global__ __launch_bounds__(384, 3)
void pair_proj_kernel(const float* __restrict__ pair,
                      const unsigned short* __restrict__ wfrag_pair,
                      const float* __restrict__ biascat, float* __restrict__ proj) {
  __shared__ __align__(16) char tAc[48 * 256 * 2];
  int tid = threadIdx.x;
  int lane = tid & 63;
  int wave = tid >> 6;
  int gm = blockIdx.x >> 3;  // (b,i) group: 48 rows
  int gn = blockIdx.x & 7;   // 96-col group

  {
    float4 pf[8];
    const float4* src = reinterpret_cast<const float4*>(pair + (size_t)gm * 12288);
#pragma unroll
    for (int it = 0; it < 4; ++it) {
      int c = it * 384 + tid;
      pf[it * 2] = src[c * 2];
      pf[it * 2 + 1] = src[c * 2 + 1];
    }
    cvt_store(tAc, tid, pf);
  }

  bf16x8 wf[8];
  {
    const bf16x8* wp = reinterpret_cast<const bf16x8*>(wfrag_pair);
#pragma unroll
    for (int kt = 0; kt < 8; ++kt) wf[kt] = wp[((gn * 6 + wave) * 8 + kt) * 64 + lane];
  }
  __syncthreads();

  f32x4 acc[3];
#pragma unroll
  for (int mt = 0; mt < 3; ++mt) acc[mt] = (f32x4){0.f, 0.f, 0.f, 0.f};
  gemm48xK(tAc, wf, acc, lane);

  int col = gn * 96 + wave * 16 + (lane & 15);
  float bias = biascat[col];
  int jb = (lane >> 4) * 4;
#pragma unroll
  for (int mt = 0; mt < 3; ++mt) {
#pragma unroll
    for (int rr = 0; rr < 4; ++rr) {
      int j = mt * 16 + jb + rr;
      proj[(size_t)(gm * 48 + j) * 768 + col] = acc[mt][rr] + bias;
    }
  }
}

// ---------------------------------------------------------------------------
// Main: one block per (b,i, 4 consecutive k).  Software-pipelined: the next
// k-slice's 48x256 f32 tile is prefetched into registers while the current
// slice runs GEMM -> scores -> softmax -> PV.
// __launch_bounds__(384,2): VGPR cap 256 — R2's (384,4) forced a 64-VGPR
// allocation and spilled the 32-reg prefetch buffer to scratch (3x slowdown).
// ---------------------------------------------------------------------------
__global__ __launch_bounds__(384, 2)
void e2e_main(const float* __restrict__ mask, const float* __restrict__ trip,
              const float* __restrict__ proj, const unsigned short* __restrict__ wfragm,
              const float* __restrict__ bsq, const float* __restrict__ bsk,
              const float* __restrict__ bsv, float* __restrict__ out) {
  __shared__ __align__(16) char tAc[48 * 256 * 2];  // 24576 B
  __shared__ float sqT[96][49];                     // [n][j], n: 0-31 sq, 32-63 sk, 64-95 sv
  __shared__ float khl[256];
  __shared__ float maskl[48];
  __shared__ float pbuf[8][48];

  int tid = threadIdx.x;
  int lane = tid & 63;
  int wave = tid >> 6;

  int bid = blockIdx.x;
  int xcd = bid & 7;
  int idx = bid >> 3;          // 0..143
  int g = xcd * 12 + idx / 12; // (b*48+i), 0..95
  int kg = idx % 12;
  int k0 = kg * KB_;
  int b = g / 48;
  int rowbase = g * 48;        // proj row of (b,i,j=0)

  // weight fragments (held across all 4 k-slices)
  bf16x8 wf[8];
  {
    const bf16x8* wp = reinterpret_cast<const bf16x8*>(wfragm);
#pragma unroll
    for (int kt = 0; kt < 8; ++kt) wf[kt] = wp[(wave * 8 + kt) * 64 + lane];
  }
  float biasn;
  {
    int n = wave * 16 + (lane & 15);
    const float* bp = (n < 32) ? bsq : (n < 64) ? bsk : bsv;
    biasn = bp[n & 31];
  }

  // prologue: prefetch first k-tile into registers
  float4 pf[8];
  {
    const float4* src = reinterpret_cast<const float4*>(trip + (size_t)(rowbase + k0) * 12288);
#pragma unroll
    for (int it = 0; it < 4; ++it) {
      int c = it * 384 + tid;
      pf[it * 2] = src[c * 2];
      pf[it * 2 + 1] = src[c * 2 + 1];
    }
  }

  for (int kk = 0; kk < KB_; ++kk) {
    int k = k0 + kk;
    int wg = rowbase + k;

    // stage current tile regs -> LDS (bf16, swizzled)
    cvt_store(tAc, tid, pf);

    // prefetch next k-tile unconditionally (clamped; in flight across the
    // whole compute chain below, drained at next iteration's cvt_store)
    {
      int pwg = (kk + 1 < KB_) ? (wg + 1) : wg;
      const float4* src = reinterpret_cast<const float4*>(trip + (size_t)pwg * 12288);
#pragma unroll
      for (int it = 0; it < 4; ++it) {
        int c = it * 384 + tid;
        pf[it * 2] = src[c * 2];
        pf[it * 2 + 1] = src[c * 2 + 1];
      }
    }

    // per-k small loads
    if (tid < 256) khl[tid] = proj[(size_t)wg * 768 + 256 + tid];
    if (tid >= 256 && tid < 304) maskl[tid - 256] = mask[(b * 48 + k) * 48 + (tid - 256)];
    __syncthreads();

    // GEMM: sq|sk|sv = tile @ [Wsq|Wsk|Wsv]
    f32x4 acc[3];
#pragma unroll
    for (int mt = 0; mt < 3; ++mt) acc[mt] = (f32x4){0.f, 0.f, 0.f, 0.f};
    gemm48xK(tAc, wf, acc, lane);

    // epilogue: sqT[n][j] = acc + bias  (wave w owns n = w*16 .. w*16+15)
    {
      int n = wave * 16 + (lane & 15);
      int jb = (lane >> 4) * 4;
#pragma unroll
      for (int mt = 0; mt < 3; ++mt) {
#pragma unroll
        for (int rr = 0; rr < 4; ++rr) sqT[n][mt * 16 + jb + rr] = acc[mt][rr] + biasn;
      }
    }
    __syncthreads();

    // scores: 384 threads = 8h x 48j, f32
    {
      int j = tid % 48;
      int h = tid / 48;
      const float4* q4 = reinterpret_cast<const float4*>(proj + (size_t)(rowbase + j) * 768 + h * 32);
      float s = 0.f;
#pragma unroll
      for (int d4 = 0; d4 < 8; ++d4) {
        float4 q = q4[d4];
        int d = d4 * 4;
        s += (q.x + sqT[d + 0][j]) * (khl[h * 32 + d + 0] + sqT[32 + d + 0][j]);
        s += (q.y + sqT[d + 1][j]) * (khl[h * 32 + d + 1] + sqT[32 + d + 1][j]);
        s += (q.z + sqT[d + 2][j]) * (khl[h * 32 + d + 2] + sqT[32 + d + 2][j]);
        s += (q.w + sqT[d + 3][j]) * (khl[h * 32 + d + 3] + sqT[32 + d + 3][j]);
      }
      pbuf[h][j] = s * 0.17677669529663687f + maskl[j];  // 1/sqrt(32)
    }
    __syncthreads();

    // softmax over j per (h): waves 0..5 take rows wave, wave+6
    for (int h = wave; h < 8; h += 6) {
      float x = (lane < 48) ? pbuf[h][lane] : -INFINITY;
      float m = x;
#pragma unroll
      for (int off = 32; off; off >>= 1) m = fmaxf(m, __shfl_xor(m, off));
      float e = (lane < 48) ? __expf(x - m) : 0.f;
      float sum = e;
#pragma unroll
      for (int off = 32; off; off >>= 1) sum += __shfl_xor(sum, off);
      if (lane < 48) pbuf[h][lane] = e / sum;
    }
    __syncthreads();

    // PV: 256 threads = (h,d); v = proj_v[b,i,j, h*32+d] + sv[j][d]
    if (tid < 256) {
      int h = tid >> 5, d = tid & 31;
      const float* vbase = proj + (size_t)rowbase * 768 + 512 + tid;
      float a = 0.f;
#pragma unroll 8
      for (int j = 0; j < 48; ++j) a += pbuf[h][j] * (vbase[(size_t)j * 768] + sqT[64 + d][j]);
      out[(size_t)wg * 256 + tid] = a;
    }
    __syncthreads();  // protect sqT/pbuf/tAc before next k-slice
  }
}

// ---------------------------------------------------------------------------
extern "C" void kernel_launch(void* const* d_in, const int* in_sizes, int n_in,
                              void* d_out, int out_size, void* d_ws, size_t ws_size,
                              hipStream_t stream) {
  const float* mask = (const float*)d_in[0];
  const float* pair = (const float*)d_in[1];
  const float* trip = (const float*)d_in[2];
  const float* Wq = (const float*)d_in[3];
  const float* bq = (const float*)d_in[4];
  const float* Wk = (const float*)d_in[5];
  const float* bk = (const float*)d_in[6];
  const float* Wv = (const float*)d_in[7];
  const float* bv = (const float*)d_in[8];
  const float* Wsq = (const float*)d_in[9];
  const float* bsq = (const float*)d_in[10];
  const float* Wsk = (const float*)d_in[11];
  const float* bsk = (const float*)d_in[12];
  const float* Wsv = (const float*)d_in[13];
  const float* bsv = (const float*)d_in[14];

  char* ws = (char*)d_ws;
  float* proj = (float*)ws;                                               // 14,155,776 B
  unsigned short* wfrag_pair = (unsigned short*)(ws + 14155776);          // 393,216 B
  unsigned short* wfrag_main = (unsigned short*)(ws + 14155776 + 393216); // 49,152 B
  float* biascat = (float*)(ws + 14155776 + 393216 + 49152);              // 3,072 B

  pack_kernel<<<867, 256, 0, stream>>>(Wq, Wk, Wv, bq, bk, bv, Wsq, Wsk, Wsv,
                                       wfrag_pair, wfrag_main, biascat);
  pair_proj_kernel<<<768, 384, 0, stream>>>(pair, wfrag_pair, biascat, proj);
  e2e_main<<<1152, 384, 0, stream>>>(mask, trip, proj, wfrag_main, bsq, bsk, bsv,
                                     (float*)d_out);
}

// Round 4
// 118.399 us; speedup vs baseline: 2.4898x; 1.1244x over previous
//
#include <hip/hip_runtime.h>
#include <hip/hip_bf16.h>

// Problem constants
#define B_ 2
#define N_ 48
#define H_ 256
#define NH_ 8
#define DH_ 32
#define KS_ 6  // k-slices per main block; grid = 96*(48/KS_) = 768 = 3*256

typedef __attribute__((ext_vector_type(8))) short bf16x8;
typedef __attribute__((ext_vector_type(4))) float f32x4;

__device__ __forceinline__ unsigned short f2bf(float f) {
  unsigned u = __float_as_uint(f);
  u += 0x7FFFu + ((u >> 16) & 1u);
  return (unsigned short)(u >> 16);
}

__device__ __forceinline__ float bf2f(unsigned short u) {
  return __uint_as_float(((unsigned)u) << 16);
}

// Raw barrier WITHOUT vmcnt drain (__syncthreads would emit s_waitcnt vmcnt(0)
// and kill the triplet prefetch that we keep in flight across phases).
__device__ __forceinline__ void bar_lgkm() {
  asm volatile("s_waitcnt lgkmcnt(0)" ::: "memory");
  __builtin_amdgcn_s_barrier();
  asm volatile("" ::: "memory");
}

// ---------------------------------------------------------------------------
// P0: pack [Wq|Wk|Wv] (256x768) and [Wsq|Wsk|Wsv] (256x96) into bf16 MFMA
// B-fragment order: frag[nt][kt][lane][i] = W[kt*32 + (lane>>4)*8 + i][nt*16 + (lane&15)]
// plus biascat768 = [bq|bk|bv].
// ---------------------------------------------------------------------------
__global__ void pack_kernel(const float* __restrict__ Wq, const float* __restrict__ Wk,
                            const float* __restrict__ Wv, const float* __restrict__ bq,
                            const float* __restrict__ bk, const float* __restrict__ bv,
                            const float* __restrict__ Wsq, const float* __restrict__ Wsk,
                            const float* __restrict__ Wsv,
                            unsigned short* __restrict__ wfrag_pair,
                            unsigned short* __restrict__ wfrag_main,
                            float* __restrict__ biascat) {
  int t = blockIdx.x * 256 + threadIdx.x;
  if (t < 196608) {  // 48 ntiles * 8 ktiles * 64 lanes * 8
    int i8 = t & 7, lane = (t >> 3) & 63, kt = (t >> 9) & 7, nt = t >> 12;
    int k = kt * 32 + ((lane >> 4) << 3) + i8;
    int n = nt * 16 + (lane & 15);
    const float* W = (n < 256) ? Wq : (n < 512) ? Wk : Wv;
    wfrag_pair[t] = f2bf(W[k * 256 + (n & 255)]);
  } else if (t < 196608 + 24576) {  // 6 ntiles * 8 * 64 * 8
    int p = t - 196608;
    int i8 = p & 7, lane = (p >> 3) & 63, kt = (p >> 9) & 7, nt = p >> 12;
    int k = kt * 32 + ((lane >> 4) << 3) + i8;
    int n = nt * 16 + (lane & 15);  // 0..95
    const float* W = (n < 32) ? Wsq : (n < 64) ? Wsk : Wsv;
    wfrag_main[p] = f2bf(W[k * 32 + (n & 31)]);
  } else if (t < 196608 + 24576 + 768) {
    int p = t - 196608 - 24576;
    const float* bsrc = (p < 256) ? bq : (p < 512) ? bk : bv;
    biascat[p] = bsrc[p & 255];
  }
}

// ---------------------------------------------------------------------------
// Shared helpers. LDS tile layout: bf16, row<<9 + col*2, XOR-swizzled by
// (row&7)<<4 (applied on both write and read sides).
// ---------------------------------------------------------------------------
__device__ __forceinline__ void gemm48xK(const char* tAc, const bf16x8* wf, f32x4 acc[3], int lane) {
#pragma unroll
  for (int kt = 0; kt < 8; ++kt) {
#pragma unroll
    for (int mt = 0; mt < 3; ++mt) {
      int row = mt * 16 + (lane & 15);
      int off = (row << 9) + (kt << 6) + ((lane >> 4) << 4);
      off ^= (row & 7) << 4;
      bf16x8 a = *reinterpret_cast<const bf16x8*>(tAc + off);
      acc[mt] = __builtin_amdgcn_mfma_f32_16x16x32_bf16(a, wf[kt], acc[mt], 0, 0, 0);
    }
  }
}

__device__ __forceinline__ void cvt_store(char* tAc, int tid, const float4 pf[8]) {
#pragma unroll
  for (int it = 0; it < 4; ++it) {
    int c = it * 384 + tid;
    int row = c >> 5;
    int off = (row << 9) + ((c & 31) << 4);
    off ^= (row & 7) << 4;
    float4 x = pf[it * 2], y = pf[it * 2 + 1];
    union { unsigned short us[8]; bf16x8 v; } o;
    o.us[0] = f2bf(x.x); o.us[1] = f2bf(x.y); o.us[2] = f2bf(x.z); o.us[3] = f2bf(x.w);
    o.us[4] = f2bf(y.x); o.us[5] = f2bf(y.y); o.us[6] = f2bf(y.z); o.us[7] = f2bf(y.w);
    *reinterpret_cast<bf16x8*>(tAc + off) = o.v;
  }
}

// ---------------------------------------------------------------------------
// A: pair projections.  proj[(b*48+i)*48+j][0:256]=q, [256:512]=k, [512:768]=v
// ---------------------------------------------------------------------------
__global__ __launch_bounds__(384, 3)
void pair_proj_kernel(const float* __restrict__ pair,
                      const unsigned short* __restrict__ wfrag_pair,
                      const float* __restrict__ biascat, float* __restrict__ proj) {
  __shared__ __align__(16) char tAc[48 * 256 * 2];
  int tid = threadIdx.x;
  int lane = tid & 63;
  int wave = tid >> 6;
  int gm = blockIdx.x >> 3;  // (b,i) group: 48 rows
  int gn = blockIdx.x & 7;   // 96-col group

  {
    float4 pf[8];
    const float4* src = reinterpret_cast<const float4*>(pair + (size_t)gm * 12288);
#pragma unroll
    for (int it = 0; it < 4; ++it) {
      int c = it * 384 + tid;
      pf[it * 2] = src[c * 2];
      pf[it * 2 + 1] = src[c * 2 + 1];
    }
    cvt_store(tAc, tid, pf);
  }

  bf16x8 wf[8];
  {
    const bf16x8* wp = reinterpret_cast<const bf16x8*>(wfrag_pair);
#pragma unroll
    for (int kt = 0; kt < 8; ++kt) wf[kt] = wp[((gn * 6 + wave) * 8 + kt) * 64 + lane];
  }
  __syncthreads();

  f32x4 acc[3];
#pragma unroll
  for (int mt = 0; mt < 3; ++mt) acc[mt] = (f32x4){0.f, 0.f, 0.f, 0.f};
  gemm48xK(tAc, wf, acc, lane);

  int col = gn * 96 + wave * 16 + (lane & 15);
  float bias = biascat[col];
  int jb = (lane >> 4) * 4;
#pragma unroll
  for (int mt = 0; mt < 3; ++mt) {
#pragma unroll
    for (int rr = 0; rr < 4; ++rr) {
      int j = mt * 16 + jb + rr;
      proj[(size_t)(gm * 48 + j) * 768 + col] = acc[mt][rr] + bias;
    }
  }
}

// ---------------------------------------------------------------------------
// Main: one block per (b,i, 6 consecutive k). grid = 768 = 3 * 256 CUs.
// Prologue hoists all (b,i)-shared data: v-rows -> LDS bf16, k-rows (6
// slices) -> LDS f32, q-row -> 32 persistent VGPRs, mask -> LDS.
// Per slice the ONLY global traffic is the in-flight triplet prefetch (kept
// alive across raw barriers) and the final out store.
// bid -> xcd = bid&7; all 8 k-groups of one (b,i) land on the same XCD.
// ---------------------------------------------------------------------------
__global__ __launch_bounds__(384, 3)
void e2e_main(const float* __restrict__ mask, const float* __restrict__ trip,
              const float* __restrict__ proj, const unsigned short* __restrict__ wfragm,
              const float* __restrict__ bsq, const float* __restrict__ bsk,
              const float* __restrict__ bsv, float* __restrict__ out) {
  __shared__ __align__(16) char tAc[48 * 256 * 2];       // 24576 B
  __shared__ float sqT[96][49];                          // 18816 B
  __shared__ __align__(16) unsigned short vbf[48 * 256]; // 24576 B
  __shared__ float khlall[KS_][256];                     // 6144 B
  __shared__ float maskall[KS_][48];                     // 1152 B
  __shared__ float pbuf[8][48];                          // 1536 B  -> 76800 B total

  int tid = threadIdx.x;
  int lane = tid & 63;
  int wave = tid >> 6;

  int bid = blockIdx.x;
  int xcd = bid & 7;
  int slot = bid >> 3;              // 0..95
  int g = xcd * 12 + (slot >> 3);   // (b*48+i), 0..95
  int kg = slot & 7;                // 0..7
  int k0 = kg * KS_;
  int b = g / 48;
  int rowbase = g * 48;

  // --- prologue: block-persistent register state ---
  bf16x8 wf[8];
  {
    const bf16x8* wp = reinterpret_cast<const bf16x8*>(wfragm);
#pragma unroll
    for (int kt = 0; kt < 8; ++kt) wf[kt] = wp[(wave * 8 + kt) * 64 + lane];
  }
  float biasn;
  {
    int n = wave * 16 + (lane & 15);
    const float* bp = (n < 32) ? bsq : (n < 64) ? bsk : bsv;
    biasn = bp[n & 31];
  }
  // q-row for this thread's (j,h) scores role, held in regs for all slices
  int jj = tid % 48, hh = tid / 48;
  float4 qreg[8];
  {
    const float4* qsrc = reinterpret_cast<const float4*>(proj + (size_t)(rowbase + jj) * 768 + hh * 32);
#pragma unroll
    for (int d4 = 0; d4 < 8; ++d4) qreg[d4] = qsrc[d4];
  }

  // --- prologue: LDS staging (v bf16, khl 6 slices, mask) ---
#pragma unroll
  for (int it = 0; it < 8; ++it) {
    int c4 = it * 384 + tid;   // 0..3071 float4 chunks of 48x256 v block
    int j = c4 >> 6, col4 = c4 & 63;
    float4 x = *reinterpret_cast<const float4*>(proj + (size_t)(rowbase + j) * 768 + 512 + col4 * 4);
    ushort4 o;
    o.x = f2bf(x.x); o.y = f2bf(x.y); o.z = f2bf(x.z); o.w = f2bf(x.w);
    *reinterpret_cast<ushort4*>(&vbf[j * 256 + col4 * 4]) = o;
  }
#pragma unroll
  for (int it = 0; it < 4; ++it) {
    int e = it * 384 + tid;    // 0..1535
    int s = e >> 8, c = e & 255;
    khlall[s][c] = proj[(size_t)(rowbase + k0 + s) * 768 + 256 + c];
  }
  if (tid < KS_ * 48) maskall[tid / 48][tid % 48] = mask[(b * 48 + k0 + tid / 48) * 48 + tid % 48];

  // prefetch slice 0 triplet tile (stays in flight across the barrier)
  float4 pf[8];
  {
    const float4* src = reinterpret_cast<const float4*>(trip + (size_t)(rowbase + k0) * 12288);
#pragma unroll
    for (int it = 0; it < 4; ++it) {
      int c = it * 384 + tid;
      pf[it * 2] = src[c * 2];
      pf[it * 2 + 1] = src[c * 2 + 1];
    }
  }
  bar_lgkm();

  for (int kk = 0; kk < KS_; ++kk) {
    int wg = rowbase + k0 + kk;

    // stage current tile regs -> LDS (drains this slice's pf loads only)
    cvt_store(tAc, tid, pf);

    // prefetch next slice's tile; in flight across ALL phases below
    {
      int pwg = (kk + 1 < KS_) ? (wg + 1) : wg;
      const float4* src = reinterpret_cast<const float4*>(trip + (size_t)pwg * 12288);
#pragma unroll
      for (int it = 0; it < 4; ++it) {
        int c = it * 384 + tid;
        pf[it * 2] = src[c * 2];
        pf[it * 2 + 1] = src[c * 2 + 1];
      }
    }
    bar_lgkm();

    // GEMM: sq|sk|sv = tile @ [Wsq|Wsk|Wsv]
    f32x4 acc[3];
#pragma unroll
    for (int mt = 0; mt < 3; ++mt) acc[mt] = (f32x4){0.f, 0.f, 0.f, 0.f};
    gemm48xK(tAc, wf, acc, lane);

    // epilogue: sqT[n][j] = acc + bias  (wave w owns n = w*16 .. w*16+15)
    {
      int n = wave * 16 + (lane & 15);
      int jb = (lane >> 4) * 4;
#pragma unroll
      for (int mt = 0; mt < 3; ++mt) {
#pragma unroll
        for (int rr = 0; rr < 4; ++rr) sqT[n][mt * 16 + jb + rr] = acc[mt][rr] + biasn;
      }
    }
    bar_lgkm();

    // scores: 384 threads = (hh, jj); all operands regs/LDS
    {
      float s = 0.f;
#pragma unroll
      for (int d4 = 0; d4 < 8; ++d4) {
        float4 q = qreg[d4];
        int d = d4 * 4;
        s += (q.x + sqT[d + 0][jj]) * (khlall[kk][hh * 32 + d + 0] + sqT[32 + d + 0][jj]);
        s += (q.y + sqT[d + 1][jj]) * (khlall[kk][hh * 32 + d + 1] + sqT[32 + d + 1][jj]);
        s += (q.z + sqT[d + 2][jj]) * (khlall[kk][hh * 32 + d + 2] + sqT[32 + d + 2][jj]);
        s += (q.w + sqT[d + 3][jj]) * (khlall[kk][hh * 32 + d + 3] + sqT[32 + d + 3][jj]);
      }
      pbuf[hh][jj] = s * 0.17677669529663687f + maskall[kk][jj];  // 1/sqrt(32)
    }
    bar_lgkm();

    // softmax over j per head: waves 0..5 take rows wave, wave+6
    for (int h = wave; h < 8; h += 6) {
      float x = (lane < 48) ? pbuf[h][lane] : -INFINITY;
      float m = x;
#pragma unroll
      for (int off = 32; off; off >>= 1) m = fmaxf(m, __shfl_xor(m, off));
      float e = (lane < 48) ? __expf(x - m) : 0.f;
      float sum = e;
#pragma unroll
      for (int off = 32; off; off >>= 1) sum += __shfl_xor(sum, off);
      if (lane < 48) pbuf[h][lane] = e / sum;
    }
    bar_lgkm();

    // PV: 256 threads = (h,d); v from LDS bf16, sv from sqT
    if (tid < 256) {
      int h = tid >> 5, d = tid & 31;
      float a = 0.f;
#pragma unroll 8
      for (int j = 0; j < 48; ++j)
        a += pbuf[h][j] * (bf2f(vbf[j * 256 + tid]) + sqT[64 + d][j]);
      out[(size_t)wg * 256 + tid] = a;
    }
    // no trailing barrier: next slice's first LDS writes (tAc) are WAR-safe
    // (tAc last read pre-GEMM-barrier); sqT/pbuf rewrites are behind the
    // next slice's own barriers.
  }
}

// ---------------------------------------------------------------------------
extern "C" void kernel_launch(void* const* d_in, const int* in_sizes, int n_in,
                              void* d_out, int out_size, void* d_ws, size_t ws_size,
                              hipStream_t stream) {
  const float* mask = (const float*)d_in[0];
  const float* pair = (const float*)d_in[1];
  const float* trip = (const float*)d_in[2];
  const float* Wq = (const float*)d_in[3];
  const float* bq = (const float*)d_in[4];
  const float* Wk = (const float*)d_in[5];
  const float* bk = (const float*)d_in[6];
  const float* Wv = (const float*)d_in[7];
  const float* bv = (const float*)d_in[8];
  const float* Wsq = (const float*)d_in[9];
  const float* bsq = (const float*)d_in[10];
  const float* Wsk = (const float*)d_in[11];
  const float* bsk = (const float*)d_in[12];
  const float* Wsv = (const float*)d_in[13];
  const float* bsv = (const float*)d_in[14];

  char* ws = (char*)d_ws;
  float* proj = (float*)ws;                                               // 14,155,776 B
  unsigned short* wfrag_pair = (unsigned short*)(ws + 14155776);          // 393,216 B
  unsigned short* wfrag_main = (unsigned short*)(ws + 14155776 + 393216); // 49,152 B
  float* biascat = (float*)(ws + 14155776 + 393216 + 49152);              // 3,072 B

  pack_kernel<<<867, 256, 0, stream>>>(Wq, Wk, Wv, bq, bk, bv, Wsq, Wsk, Wsv,
                                       wfrag_pair, wfrag_main, biascat);
  pair_proj_kernel<<<768, 384, 0, stream>>>(pair, wfrag_pair, biascat, proj);
  e2e_main<<<768, 384, 0, stream>>>(mask, trip, proj, wfrag_main, bsq, bsk, bsv,
                                    (float*)d_out);
}

// Round 5
// 111.644 us; speedup vs baseline: 2.6405x; 1.0605x over previous
//
#include <hip/hip_runtime.h>
#include <hip/hip_bf16.h>

// Problem constants
#define B_ 2
#define N_ 48
#define H_ 256
#define NH_ 8
#define DH_ 32

typedef __attribute__((ext_vector_type(8))) short bf16x8;
typedef __attribute__((ext_vector_type(4))) float f32x4;

__device__ __forceinline__ unsigned short f2bf(float f) {
  unsigned u = __float_as_uint(f);
  u += 0x7FFFu + ((u >> 16) & 1u);
  return (unsigned short)(u >> 16);
}

// ---------------------------------------------------------------------------
// P0: pack [Wq|Wk|Wv] (256x768) and [Wsq|Wsk|Wsv] (256x96) into bf16 MFMA
// B-fragment order: frag[nt][kt][lane][i] = W[kt*32 + (lane>>4)*8 + i][nt*16 + (lane&15)]
// plus biascat768 = [bq|bk|bv].
// ---------------------------------------------------------------------------
__global__ void pack_kernel(const float* __restrict__ Wq, const float* __restrict__ Wk,
                            const float* __restrict__ Wv, const float* __restrict__ bq,
                            const float* __restrict__ bk, const float* __restrict__ bv,
                            const float* __restrict__ Wsq, const float* __restrict__ Wsk,
                            const float* __restrict__ Wsv,
                            unsigned short* __restrict__ wfrag_pair,
                            unsigned short* __restrict__ wfrag_main,
                            float* __restrict__ biascat) {
  int t = blockIdx.x * 256 + threadIdx.x;
  if (t < 196608) {  // 48 ntiles * 8 ktiles * 64 lanes * 8
    int i8 = t & 7, lane = (t >> 3) & 63, kt = (t >> 9) & 7, nt = t >> 12;
    int k = kt * 32 + ((lane >> 4) << 3) + i8;
    int n = nt * 16 + (lane & 15);
    const float* W = (n < 256) ? Wq : (n < 512) ? Wk : Wv;
    wfrag_pair[t] = f2bf(W[k * 256 + (n & 255)]);
  } else if (t < 196608 + 24576) {  // 6 ntiles * 8 * 64 * 8
    int p = t - 196608;
    int i8 = p & 7, lane = (p >> 3) & 63, kt = (p >> 9) & 7, nt = p >> 12;
    int k = kt * 32 + ((lane >> 4) << 3) + i8;
    int n = nt * 16 + (lane & 15);  // 0..95
    const float* W = (n < 32) ? Wsq : (n < 64) ? Wsk : Wsv;
    wfrag_main[p] = f2bf(W[k * 32 + (n & 31)]);
  } else if (t < 196608 + 24576 + 768) {
    int p = t - 196608 - 24576;
    const float* bsrc = (p < 256) ? bq : (p < 512) ? bk : bv;
    biascat[p] = bsrc[p & 255];
  }
}

// ---------------------------------------------------------------------------
// Shared helpers. LDS tile layout: bf16, row<<9 + col*2, XOR-swizzled by
// (row&7)<<4 (applied on both write and read sides).
// ---------------------------------------------------------------------------
__device__ __forceinline__ void stage48x256(const float* __restrict__ src, char* tAc, int tid) {
#pragma unroll
  for (int it = 0; it < 4; ++it) {
    int c = it * 384 + tid;  // 16-byte bf16 chunk id, 0..1535
    const float4* g = reinterpret_cast<const float4*>(src) + (c << 1);
    float4 x = g[0];
    float4 y = g[1];
    int row = c >> 5;
    int off = (row << 9) + ((c & 31) << 4);
    off ^= (row & 7) << 4;
    union { unsigned short us[8]; bf16x8 v; } o;
    o.us[0] = f2bf(x.x); o.us[1] = f2bf(x.y); o.us[2] = f2bf(x.z); o.us[3] = f2bf(x.w);
    o.us[4] = f2bf(y.x); o.us[5] = f2bf(y.y); o.us[6] = f2bf(y.z); o.us[7] = f2bf(y.w);
    *reinterpret_cast<bf16x8*>(tAc + off) = o.v;
  }
}

// ---------------------------------------------------------------------------
// A: pair projections.  proj[(b*48+i)*48+j][0:256]=q, [256:512]=k, [512:768]=v
// ---------------------------------------------------------------------------
__global__ __launch_bounds__(384, 3)
void pair_proj_kernel(const float* __restrict__ pair,
                      const unsigned short* __restrict__ wfrag_pair,
                      const float* __restrict__ biascat, float* __restrict__ proj) {
  __shared__ __align__(16) char tAc[48 * 256 * 2];
  int tid = threadIdx.x;
  int lane = tid & 63;
  int wave = tid >> 6;
  int gm = blockIdx.x >> 3;  // (b,i) group: 48 rows
  int gn = blockIdx.x & 7;   // 96-col group

  stage48x256(pair + (size_t)gm * 12288, tAc, tid);

  bf16x8 wf[8];
  {
    const bf16x8* wp = reinterpret_cast<const bf16x8*>(wfrag_pair);
#pragma unroll
    for (int kt = 0; kt < 8; ++kt) wf[kt] = wp[((gn * 6 + wave) * 8 + kt) * 64 + lane];
  }
  __syncthreads();

  f32x4 acc[3];
#pragma unroll
  for (int mt = 0; mt < 3; ++mt) acc[mt] = (f32x4){0.f, 0.f, 0.f, 0.f};
#pragma unroll
  for (int kt = 0; kt < 8; ++kt) {
#pragma unroll
    for (int mt = 0; mt < 3; ++mt) {
      int row = mt * 16 + (lane & 15);
      int off = (row << 9) + (kt << 6) + ((lane >> 4) << 4);
      off ^= (row & 7) << 4;
      bf16x8 a = *reinterpret_cast<const bf16x8*>(tAc + off);
      acc[mt] = __builtin_amdgcn_mfma_f32_16x16x32_bf16(a, wf[kt], acc[mt], 0, 0, 0);
    }
  }

  int col = gn * 96 + wave * 16 + (lane & 15);
  float bias = biascat[col];
  int jb = (lane >> 4) * 4;
#pragma unroll
  for (int mt = 0; mt < 3; ++mt) {
#pragma unroll
    for (int rr = 0; rr < 4; ++rr) {
      int j = mt * 16 + jb + rr;
      proj[(size_t)(gm * 48 + j) * 768 + col] = acc[mt][rr] + bias;
    }
  }
}

// ---------------------------------------------------------------------------
// A2: triplet GEMM (streaming).  One (b,i,k) slice per block: stage 48x256
// f32 -> bf16 LDS, one barrier, 24 MFMA/wave (wave = n-tile; weights loaded
// per-kt from L2 to stay under 64 VGPR), write sq|sk|sv bf16 TRANSPOSED
// [n(96)][j(48)] (+bias folded) to workspace.  No attention phases.
// ---------------------------------------------------------------------------
__global__ __launch_bounds__(384, 8)
void trip_gemm(const float* __restrict__ trip, const unsigned short* __restrict__ wfragm,
               const float* __restrict__ bsq, const float* __restrict__ bsk,
               const float* __restrict__ bsv, unsigned short* __restrict__ sqkv) {
  __shared__ __align__(16) char tAc[48 * 256 * 2];  // 24576 B
  __shared__ float biasl[96];

  int tid = threadIdx.x;
  int lane = tid & 63;
  int wave = tid >> 6;
  int slice = blockIdx.x;  // (b*48+i)*48 + k

  stage48x256(trip + (size_t)slice * 12288, tAc, tid);
  if (tid < 96) biasl[tid] = (tid < 32) ? bsq[tid] : (tid < 64) ? bsk[tid - 32] : bsv[tid - 64];
  __syncthreads();

  const bf16x8* wp = reinterpret_cast<const bf16x8*>(wfragm);
  f32x4 acc[3];
#pragma unroll
  for (int mt = 0; mt < 3; ++mt) acc[mt] = (f32x4){0.f, 0.f, 0.f, 0.f};
#pragma unroll
  for (int kt = 0; kt < 8; ++kt) {
    bf16x8 w = wp[(wave * 8 + kt) * 64 + lane];  // L2-hot, 16B/lane
#pragma unroll
    for (int mt = 0; mt < 3; ++mt) {
      int row = mt * 16 + (lane & 15);
      int off = (row << 9) + (kt << 6) + ((lane >> 4) << 4);
      off ^= (row & 7) << 4;
      bf16x8 a = *reinterpret_cast<const bf16x8*>(tAc + off);
      acc[mt] = __builtin_amdgcn_mfma_f32_16x16x32_bf16(a, w, acc[mt], 0, 0, 0);
    }
  }

  // epilogue: n = wave*16+(lane&15) owns rows j = mt*16 + jb + 0..3
  int n = wave * 16 + (lane & 15);
  float bias = biasl[n];
  int jb = (lane >> 4) * 4;
  unsigned short* dst = sqkv + (size_t)slice * 4608 + n * 48;
#pragma unroll
  for (int mt = 0; mt < 3; ++mt) {
    ushort4 o;
    o.x = f2bf(acc[mt][0] + bias);
    o.y = f2bf(acc[mt][1] + bias);
    o.z = f2bf(acc[mt][2] + bias);
    o.w = f2bf(acc[mt][3] + bias);
    *reinterpret_cast<ushort4*>(dst + mt * 16 + jb) = o;
  }
}

// ---------------------------------------------------------------------------
// B: attention (no MFMA, VGPR-light, 5 blocks/CU).  One (b,i,k) per block.
// Stage sqkv slice (bf16 [96][48] -> f32 LDS [96][49]), k-row, mask; then
// scores (8h x 48j, q from L2) -> softmax -> PV (v from L2) -> out.
// XCD swizzle: 4608 = 8*576; same-(b,i) slices share an XCD for q/v L2 reuse.
// ---------------------------------------------------------------------------
__global__ __launch_bounds__(384, 8)
void attn_kernel(const float* __restrict__ mask, const float* __restrict__ proj,
                 const unsigned short* __restrict__ sqkv, float* __restrict__ out) {
  __shared__ float sqT[96][49];  // 18816 B  (0-31 sq, 32-63 sk, 64-95 sv)
  __shared__ float pbuf[8][48];
  __shared__ float khl[256];
  __shared__ float maskl[48];

  int tid = threadIdx.x;
  int lane = tid & 63;
  int wave = tid >> 6;

  int bid = blockIdx.x;
  int s = (bid & 7) * 576 + (bid >> 3);  // slice = (b*48+i)*48 + k
  int g = s / 48;                        // (b*48+i)
  int k = s % 48;
  int b = g / 48;
  int rowbase = g * 48;

  // stage sqkv slice: 1152 ushort4 chunks
  {
    const ushort4* src = reinterpret_cast<const ushort4*>(sqkv + (size_t)s * 4608);
#pragma unroll
    for (int it = 0; it < 3; ++it) {
      int e = it * 384 + tid;  // 0..1151
      ushort4 v = src[e];
      int n = e / 12, j = (e % 12) * 4;
      sqT[n][j + 0] = __uint_as_float((unsigned)v.x << 16);
      sqT[n][j + 1] = __uint_as_float((unsigned)v.y << 16);
      sqT[n][j + 2] = __uint_as_float((unsigned)v.z << 16);
      sqT[n][j + 3] = __uint_as_float((unsigned)v.w << 16);
    }
  }
  if (tid < 256) khl[tid] = proj[(size_t)s * 768 + 256 + tid];
  if (tid >= 256 && tid < 304) maskl[tid - 256] = mask[b * 2304 + k * 48 + (tid - 256)];
  __syncthreads();

  // scores: thread (h = tid/48, j = tid%48)
  {
    int j = tid % 48, h = tid / 48;
    const float4* q4 = reinterpret_cast<const float4*>(proj + (size_t)(rowbase + j) * 768 + h * 32);
    float sc = 0.f;
#pragma unroll
    for (int d4 = 0; d4 < 8; ++d4) {
      float4 q = q4[d4];
      int d = d4 * 4;
      sc += (q.x + sqT[d + 0][j]) * (khl[h * 32 + d + 0] + sqT[32 + d + 0][j]);
      sc += (q.y + sqT[d + 1][j]) * (khl[h * 32 + d + 1] + sqT[32 + d + 1][j]);
      sc += (q.z + sqT[d + 2][j]) * (khl[h * 32 + d + 2] + sqT[32 + d + 2][j]);
      sc += (q.w + sqT[d + 3][j]) * (khl[h * 32 + d + 3] + sqT[32 + d + 3][j]);
    }
    pbuf[h][j] = sc * 0.17677669529663687f + maskl[j];  // 1/sqrt(32)
  }
  __syncthreads();

  // softmax over j per head: waves 0..5 take rows wave, wave+6
  for (int h = wave; h < 8; h += 6) {
    float x = (lane < 48) ? pbuf[h][lane] : -INFINITY;
    float m = x;
#pragma unroll
    for (int off = 32; off; off >>= 1) m = fmaxf(m, __shfl_xor(m, off));
    float e = (lane < 48) ? __expf(x - m) : 0.f;
    float sum = e;
#pragma unroll
    for (int off = 32; off; off >>= 1) sum += __shfl_xor(sum, off);
    if (lane < 48) pbuf[h][lane] = e / sum;
  }
  __syncthreads();

  // PV: 256 threads = (h,d); v rows from L2 (256B/wave per j, coalesced)
  if (tid < 256) {
    int h = tid >> 5, d = tid & 31;
    const float* vbase = proj + (size_t)rowbase * 768 + 512 + tid;
    float a = 0.f;
#pragma unroll 8
    for (int j = 0; j < 48; ++j) a += pbuf[h][j] * (vbase[(size_t)j * 768] + sqT[64 + d][j]);
    out[(size_t)s * 256 + tid] = a;
  }
}

// ---------------------------------------------------------------------------
extern "C" void kernel_launch(void* const* d_in, const int* in_sizes, int n_in,
                              void* d_out, int out_size, void* d_ws, size_t ws_size,
                              hipStream_t stream) {
  const float* mask = (const float*)d_in[0];
  const float* pair = (const float*)d_in[1];
  const float* trip = (const float*)d_in[2];
  const float* Wq = (const float*)d_in[3];
  const float* bq = (const float*)d_in[4];
  const float* Wk = (const float*)d_in[5];
  const float* bk = (const float*)d_in[6];
  const float* Wv = (const float*)d_in[7];
  const float* bv = (const float*)d_in[8];
  const float* Wsq = (const float*)d_in[9];
  const float* bsq = (const float*)d_in[10];
  const float* Wsk = (const float*)d_in[11];
  const float* bsk = (const float*)d_in[12];
  const float* Wsv = (const float*)d_in[13];
  const float* bsv = (const float*)d_in[14];

  char* ws = (char*)d_ws;
  float* proj = (float*)ws;                                               // 14,155,776 B
  unsigned short* wfrag_pair = (unsigned short*)(ws + 14155776);          // 393,216 B
  unsigned short* wfrag_main = (unsigned short*)(ws + 14155776 + 393216); // 49,152 B
  float* biascat = (float*)(ws + 14155776 + 393216 + 49152);              // 3,072 B
  unsigned short* sqkv = (unsigned short*)(ws + 14601216);                // 42,467,328 B

  pack_kernel<<<867, 256, 0, stream>>>(Wq, Wk, Wv, bq, bk, bv, Wsq, Wsk, Wsv,
                                       wfrag_pair, wfrag_main, biascat);
  pair_proj_kernel<<<768, 384, 0, stream>>>(pair, wfrag_pair, biascat, proj);
  trip_gemm<<<4608, 384, 0, stream>>>(trip, wfrag_main, bsq, bsk, bsv, sqkv);
  attn_kernel<<<4608, 384, 0, stream>>>(mask, proj, sqkv, (float*)d_out);
}

// Round 6
// 86.637 us; speedup vs baseline: 3.4026x; 1.2886x over previous
//
#include <hip/hip_runtime.h>
#include <hip/hip_bf16.h>

// Problem constants
#define B_ 2
#define N_ 48
#define H_ 256
#define NH_ 8
#define DH_ 32

typedef __attribute__((ext_vector_type(8))) short bf16x8;
typedef __attribute__((ext_vector_type(4))) float f32x4;

__device__ __forceinline__ unsigned short f2bf(float f) {
  unsigned u = __float_as_uint(f);
  u += 0x7FFFu + ((u >> 16) & 1u);
  return (unsigned short)(u >> 16);
}

// ---------------------------------------------------------------------------
// P0: pack [Wq|Wk|Wv] (256x768) and [Wsq|Wsk|Wsv] (256x96) into bf16 MFMA
// B-fragment order: frag[nt][kt][lane][i] = W[kt*32 + (lane>>4)*8 + i][nt*16 + (lane&15)]
// plus biascat768 = [bq|bk|bv] and biasm96 = [bsq|bsk|bsv].
// ---------------------------------------------------------------------------
__global__ void pack_kernel(const float* __restrict__ Wq, const float* __restrict__ Wk,
                            const float* __restrict__ Wv, const float* __restrict__ bq,
                            const float* __restrict__ bk, const float* __restrict__ bv,
                            const float* __restrict__ Wsq, const float* __restrict__ Wsk,
                            const float* __restrict__ Wsv, const float* __restrict__ bsq,
                            const float* __restrict__ bsk, const float* __restrict__ bsv,
                            unsigned short* __restrict__ wfrag_pair,
                            unsigned short* __restrict__ wfrag_main,
                            float* __restrict__ biascat, float* __restrict__ biasm) {
  int t = blockIdx.x * 256 + threadIdx.x;
  if (t < 196608) {  // 48 ntiles * 8 ktiles * 64 lanes * 8
    int i8 = t & 7, lane = (t >> 3) & 63, kt = (t >> 9) & 7, nt = t >> 12;
    int k = kt * 32 + ((lane >> 4) << 3) + i8;
    int n = nt * 16 + (lane & 15);
    const float* W = (n < 256) ? Wq : (n < 512) ? Wk : Wv;
    wfrag_pair[t] = f2bf(W[k * 256 + (n & 255)]);
  } else if (t < 196608 + 24576) {  // 6 ntiles * 8 * 64 * 8
    int p = t - 196608;
    int i8 = p & 7, lane = (p >> 3) & 63, kt = (p >> 9) & 7, nt = p >> 12;
    int k = kt * 32 + ((lane >> 4) << 3) + i8;
    int n = nt * 16 + (lane & 15);  // 0..95
    const float* W = (n < 32) ? Wsq : (n < 64) ? Wsk : Wsv;
    wfrag_main[p] = f2bf(W[k * 32 + (n & 31)]);
  } else if (t < 196608 + 24576 + 768) {
    int p = t - 196608 - 24576;
    const float* bsrc = (p < 256) ? bq : (p < 512) ? bk : bv;
    biascat[p] = bsrc[p & 255];
  } else if (t < 196608 + 24576 + 768 + 96) {
    int p = t - 196608 - 24576 - 768;
    biasm[p] = (p < 32) ? bsq[p] : (p < 64) ? bsk[p - 32] : bsv[p - 64];
  }
}

// ---------------------------------------------------------------------------
// Stage a 48x256 f32 tile -> bf16 LDS.  Layout: byte = row*512 + col*2,
// XOR-swizzled by (row&7)<<4 (both write and read sides).
// ---------------------------------------------------------------------------
__device__ __forceinline__ void stage48x256(const float* __restrict__ src, char* tAc, int tid) {
#pragma unroll
  for (int it = 0; it < 4; ++it) {
    int c = it * 384 + tid;  // 16-byte bf16 chunk id, 0..1535
    const float4* g = reinterpret_cast<const float4*>(src) + (c << 1);
    float4 x = g[0];
    float4 y = g[1];
    int row = c >> 5;
    int off = (row << 9) + ((c & 31) << 4);
    off ^= (row & 7) << 4;
    union { unsigned short us[8]; bf16x8 v; } o;
    o.us[0] = f2bf(x.x); o.us[1] = f2bf(x.y); o.us[2] = f2bf(x.z); o.us[3] = f2bf(x.w);
    o.us[4] = f2bf(y.x); o.us[5] = f2bf(y.y); o.us[6] = f2bf(y.z); o.us[7] = f2bf(y.w);
    *reinterpret_cast<bf16x8*>(tAc + off) = o.v;
  }
}

// ---------------------------------------------------------------------------
// A: pair projections.  proj[(b*48+i)*48+j][0:256]=q, [256:512]=k, [512:768]=v
// ---------------------------------------------------------------------------
__global__ __launch_bounds__(384, 3)
void pair_proj_kernel(const float* __restrict__ pair,
                      const unsigned short* __restrict__ wfrag_pair,
                      const float* __restrict__ biascat, float* __restrict__ proj) {
  __shared__ __align__(16) char tAc[48 * 256 * 2];
  int tid = threadIdx.x;
  int lane = tid & 63;
  int wave = tid >> 6;
  int gm = blockIdx.x >> 3;  // (b,i) group: 48 rows
  int gn = blockIdx.x & 7;   // 96-col group

  stage48x256(pair + (size_t)gm * 12288, tAc, tid);

  bf16x8 wf[8];
  {
    const bf16x8* wp = reinterpret_cast<const bf16x8*>(wfrag_pair);
#pragma unroll
    for (int kt = 0; kt < 8; ++kt) wf[kt] = wp[((gn * 6 + wave) * 8 + kt) * 64 + lane];
  }
  __syncthreads();

  f32x4 acc[3];
#pragma unroll
  for (int mt = 0; mt < 3; ++mt) acc[mt] = (f32x4){0.f, 0.f, 0.f, 0.f};
#pragma unroll
  for (int kt = 0; kt < 8; ++kt) {
#pragma unroll
    for (int mt = 0; mt < 3; ++mt) {
      int row = mt * 16 + (lane & 15);
      int off = (row << 9) + (kt << 6) + ((lane >> 4) << 4);
      off ^= (row & 7) << 4;
      bf16x8 a = *reinterpret_cast<const bf16x8*>(tAc + off);
      acc[mt] = __builtin_amdgcn_mfma_f32_16x16x32_bf16(a, wf[kt], acc[mt], 0, 0, 0);
    }
  }

  int col = gn * 96 + wave * 16 + (lane & 15);
  float bias = biascat[col];
  int jb = (lane >> 4) * 4;
#pragma unroll
  for (int mt = 0; mt < 3; ++mt) {
#pragma unroll
    for (int rr = 0; rr < 4; ++rr) {
      int j = mt * 16 + jb + rr;
      proj[(size_t)(gm * 48 + j) * 768 + col] = acc[mt][rr] + bias;
    }
  }
}

// ---------------------------------------------------------------------------
// Fused main: one block per (b,i,k) slice; 4608 blocks.  Occupancy-first:
// VGPR-light (weights per-kt from L2, no reg prefetch, transient q/v loads)
// and LDS union (sqT overwrites tAc after GEMM) -> 27.1 KB, target 4
// blocks/CU (24 waves) so cross-block TLP hides the phase chain.
// Phases: stage -> GEMM -> epilogue(sqT) -> scores -> softmax -> PV.
// XCD swizzle: same-(b,i) slices share an XCD for q/v L2 reuse.
// ---------------------------------------------------------------------------
__global__ __launch_bounds__(384, 6)
void e2e_fused(const float* __restrict__ mask, const float* __restrict__ trip,
               const float* __restrict__ proj, const unsigned short* __restrict__ wfragm,
               const float* __restrict__ biasm, float* __restrict__ out) {
  __shared__ __align__(16) char smem[48 * 256 * 2];  // tAc, later sqT[96][49]
  __shared__ float khl[256];
  __shared__ float pbuf[8][48];
  char* tAc = smem;
  float (*sqT)[49] = reinterpret_cast<float(*)[49]>(smem);  // 18816 B <= 24576

  int tid = threadIdx.x;
  int lane = tid & 63;
  int wave = tid >> 6;

  int bid = blockIdx.x;
  int s = (bid & 7) * 576 + (bid >> 3);  // slice = (b*48+i)*48 + k
  int g = s / 48;                        // (b*48+i)
  int k = s % 48;
  int b = g / 48;
  int rowbase = g * 48;

  stage48x256(trip + (size_t)s * 12288, tAc, tid);
  if (tid < 256) khl[tid] = proj[(size_t)s * 768 + 256 + tid];
  __syncthreads();  // [1] tile staged

  // GEMM: sq|sk|sv = tile @ [Wsq|Wsk|Wsv]; wave = 16-col n-tile
  const bf16x8* wp = reinterpret_cast<const bf16x8*>(wfragm);
  f32x4 acc[3];
#pragma unroll
  for (int mt = 0; mt < 3; ++mt) acc[mt] = (f32x4){0.f, 0.f, 0.f, 0.f};
#pragma unroll
  for (int kt = 0; kt < 8; ++kt) {
    bf16x8 w = wp[(wave * 8 + kt) * 64 + lane];  // L2-hot, 16B/lane
#pragma unroll
    for (int mt = 0; mt < 3; ++mt) {
      int row = mt * 16 + (lane & 15);
      int off = (row << 9) + (kt << 6) + ((lane >> 4) << 4);
      off ^= (row & 7) << 4;
      bf16x8 a = *reinterpret_cast<const bf16x8*>(tAc + off);
      acc[mt] = __builtin_amdgcn_mfma_f32_16x16x32_bf16(a, w, acc[mt], 0, 0, 0);
    }
  }
  __syncthreads();  // [2] all tAc reads done; smem may be rewritten as sqT

  // epilogue: sqT[n][j] = acc + bias  (n: 0-31 sq, 32-63 sk, 64-95 sv)
  {
    int n = wave * 16 + (lane & 15);
    float bias = biasm[n];
    int jb = (lane >> 4) * 4;
#pragma unroll
    for (int mt = 0; mt < 3; ++mt) {
#pragma unroll
      for (int rr = 0; rr < 4; ++rr) sqT[n][mt * 16 + jb + rr] = acc[mt][rr] + bias;
    }
  }
  __syncthreads();  // [3] sqT ready

  // scores: thread (h = tid/48, j = tid%48); q row transient from L2
  {
    int j = tid % 48, h = tid / 48;
    const float4* q4 = reinterpret_cast<const float4*>(proj + (size_t)(rowbase + j) * 768 + h * 32);
    float sc = 0.f;
#pragma unroll
    for (int d4 = 0; d4 < 8; ++d4) {
      float4 q = q4[d4];
      int d = d4 * 4;
      sc += (q.x + sqT[d + 0][j]) * (khl[h * 32 + d + 0] + sqT[32 + d + 0][j]);
      sc += (q.y + sqT[d + 1][j]) * (khl[h * 32 + d + 1] + sqT[32 + d + 1][j]);
      sc += (q.z + sqT[d + 2][j]) * (khl[h * 32 + d + 2] + sqT[32 + d + 2][j]);
      sc += (q.w + sqT[d + 3][j]) * (khl[h * 32 + d + 3] + sqT[32 + d + 3][j]);
    }
    pbuf[h][j] = sc * 0.17677669529663687f + mask[b * 2304 + k * 48 + j];  // 1/sqrt(32)
  }
  __syncthreads();  // [4] scores ready

  // softmax over j per head: waves 0..5 take rows wave, wave+6
  for (int h = wave; h < 8; h += 6) {
    float x = (lane < 48) ? pbuf[h][lane] : -INFINITY;
    float m = x;
#pragma unroll
    for (int off = 32; off; off >>= 1) m = fmaxf(m, __shfl_xor(m, off));
    float e = (lane < 48) ? __expf(x - m) : 0.f;
    float sum = e;
#pragma unroll
    for (int off = 32; off; off >>= 1) sum += __shfl_xor(sum, off);
    if (lane < 48) pbuf[h][lane] = e / sum;
  }
  __syncthreads();  // [5] probs ready

  // PV: 256 threads = (h,d); v rows transient from L2 (1KB contiguous per j)
  if (tid < 256) {
    int h = tid >> 5, d = tid & 31;
    const float* vbase = proj + (size_t)rowbase * 768 + 512 + tid;
    float a = 0.f;
#pragma unroll 8
    for (int j = 0; j < 48; ++j) a += pbuf[h][j] * (vbase[(size_t)j * 768] + sqT[64 + d][j]);
    out[(size_t)s * 256 + tid] = a;
  }
}

// ---------------------------------------------------------------------------
extern "C" void kernel_launch(void* const* d_in, const int* in_sizes, int n_in,
                              void* d_out, int out_size, void* d_ws, size_t ws_size,
                              hipStream_t stream) {
  const float* mask = (const float*)d_in[0];
  const float* pair = (const float*)d_in[1];
  const float* trip = (const float*)d_in[2];
  const float* Wq = (const float*)d_in[3];
  const float* bq = (const float*)d_in[4];
  const float* Wk = (const float*)d_in[5];
  const float* bk = (const float*)d_in[6];
  const float* Wv = (const float*)d_in[7];
  const float* bv = (const float*)d_in[8];
  const float* Wsq = (const float*)d_in[9];
  const float* bsq = (const float*)d_in[10];
  const float* Wsk = (const float*)d_in[11];
  const float* bsk = (const float*)d_in[12];
  const float* Wsv = (const float*)d_in[13];
  const float* bsv = (const float*)d_in[14];

  char* ws = (char*)d_ws;
  float* proj = (float*)ws;                                               // 14,155,776 B
  unsigned short* wfrag_pair = (unsigned short*)(ws + 14155776);          // 393,216 B
  unsigned short* wfrag_main = (unsigned short*)(ws + 14155776 + 393216); // 49,152 B
  float* biascat = (float*)(ws + 14155776 + 393216 + 49152);              // 3,072 B
  float* biasm = (float*)(ws + 14155776 + 393216 + 49152 + 3072);        // 384 B

  pack_kernel<<<867, 256, 0, stream>>>(Wq, Wk, Wv, bq, bk, bv, Wsq, Wsk, Wsv,
                                       bsq, bsk, bsv,
                                       wfrag_pair, wfrag_main, biascat, biasm);
  pair_proj_kernel<<<768, 384, 0, stream>>>(pair, wfrag_pair, biascat, proj);
  e2e_fused<<<4608, 384, 0, stream>>>(mask, trip, proj, wfrag_main, biasm,
                                      (float*)d_out);
}

// Round 7
// 84.146 us; speedup vs baseline: 3.5034x; 1.0296x over previous
//
#include <hip/hip_runtime.h>
#include <hip/hip_bf16.h>

// Problem constants
#define B_ 2
#define N_ 48
#define H_ 256
#define NH_ 8
#define DH_ 32
#define SQS_LD 100  // floats; 400B row stride (16B-aligned, bank-offset 4/row)

typedef __attribute__((ext_vector_type(8))) short bf16x8;
typedef __attribute__((ext_vector_type(4))) float f32x4;

__device__ __forceinline__ unsigned short f2bf(float f) {
  unsigned u = __float_as_uint(f);
  u += 0x7FFFu + ((u >> 16) & 1u);
  return (unsigned short)(u >> 16);
}

// pack 8 floats -> 8 bf16 (RNE) via v_cvt_pk_bf16_f32 (no builtin on gfx950)
__device__ __forceinline__ bf16x8 cvt8(float4 x, float4 y) {
  union { unsigned u[4]; bf16x8 v; } o;
  asm("v_cvt_pk_bf16_f32 %0, %1, %2" : "=v"(o.u[0]) : "v"(x.x), "v"(x.y));
  asm("v_cvt_pk_bf16_f32 %0, %1, %2" : "=v"(o.u[1]) : "v"(x.z), "v"(x.w));
  asm("v_cvt_pk_bf16_f32 %0, %1, %2" : "=v"(o.u[2]) : "v"(y.x), "v"(y.y));
  asm("v_cvt_pk_bf16_f32 %0, %1, %2" : "=v"(o.u[3]) : "v"(y.z), "v"(y.w));
  return o.v;
}

// ---------------------------------------------------------------------------
// P0: pack [Wq|Wk|Wv] (256x768) and [Wsq|Wsk|Wsv] (256x96) into bf16 MFMA
// B-fragment order: frag[nt][kt][lane][i] = W[kt*32 + (lane>>4)*8 + i][nt*16 + (lane&15)]
// plus biascat768 = [bq|bk|bv] and biasm96 = [bsq|bsk|bsv].
// ---------------------------------------------------------------------------
__global__ void pack_kernel(const float* __restrict__ Wq, const float* __restrict__ Wk,
                            const float* __restrict__ Wv, const float* __restrict__ bq,
                            const float* __restrict__ bk, const float* __restrict__ bv,
                            const float* __restrict__ Wsq, const float* __restrict__ Wsk,
                            const float* __restrict__ Wsv, const float* __restrict__ bsq,
                            const float* __restrict__ bsk, const float* __restrict__ bsv,
                            unsigned short* __restrict__ wfrag_pair,
                            unsigned short* __restrict__ wfrag_main,
                            float* __restrict__ biascat, float* __restrict__ biasm) {
  int t = blockIdx.x * 256 + threadIdx.x;
  if (t < 196608) {  // 48 ntiles * 8 ktiles * 64 lanes * 8
    int i8 = t & 7, lane = (t >> 3) & 63, kt = (t >> 9) & 7, nt = t >> 12;
    int k = kt * 32 + ((lane >> 4) << 3) + i8;
    int n = nt * 16 + (lane & 15);
    const float* W = (n < 256) ? Wq : (n < 512) ? Wk : Wv;
    wfrag_pair[t] = f2bf(W[k * 256 + (n & 255)]);
  } else if (t < 196608 + 24576) {  // 6 ntiles * 8 * 64 * 8
    int p = t - 196608;
    int i8 = p & 7, lane = (p >> 3) & 63, kt = (p >> 9) & 7, nt = p >> 12;
    int k = kt * 32 + ((lane >> 4) << 3) + i8;
    int n = nt * 16 + (lane & 15);  // 0..95
    const float* W = (n < 32) ? Wsq : (n < 64) ? Wsk : Wsv;
    wfrag_main[p] = f2bf(W[k * 32 + (n & 31)]);
  } else if (t < 196608 + 24576 + 768) {
    int p = t - 196608 - 24576;
    const float* bsrc = (p < 256) ? bq : (p < 512) ? bk : bv;
    biascat[p] = bsrc[p & 255];
  } else if (t < 196608 + 24576 + 768 + 96) {
    int p = t - 196608 - 24576 - 768;
    biasm[p] = (p < 32) ? bsq[p] : (p < 64) ? bsk[p - 32] : bsv[p - 64];
  }
}

// ---------------------------------------------------------------------------
// Stage a 48x256 f32 tile -> bf16 LDS.  Layout: byte = row*512 + col*2,
// XOR-swizzled by (row&7)<<4 (both write and read sides).
// ---------------------------------------------------------------------------
__device__ __forceinline__ void stage48x256(const float* __restrict__ src, char* tAc, int tid) {
#pragma unroll
  for (int it = 0; it < 4; ++it) {
    int c = it * 384 + tid;  // 16-byte bf16 chunk id, 0..1535
    const float4* g = reinterpret_cast<const float4*>(src) + (c << 1);
    float4 x = g[0];
    float4 y = g[1];
    int row = c >> 5;
    int off = (row << 9) + ((c & 31) << 4);
    off ^= (row & 7) << 4;
    *reinterpret_cast<bf16x8*>(tAc + off) = cvt8(x, y);
  }
}

// ---------------------------------------------------------------------------
// A: pair projections.  proj[(b*48+i)*48+j][0:256]=q, [256:512]=k, [512:768]=v
// ---------------------------------------------------------------------------
__global__ __launch_bounds__(384, 3)
void pair_proj_kernel(const float* __restrict__ pair,
                      const unsigned short* __restrict__ wfrag_pair,
                      const float* __restrict__ biascat, float* __restrict__ proj) {
  __shared__ __align__(16) char tAc[48 * 256 * 2];
  int tid = threadIdx.x;
  int lane = tid & 63;
  int wave = tid >> 6;
  int gm = blockIdx.x >> 3;  // (b,i) group: 48 rows
  int gn = blockIdx.x & 7;   // 96-col group

  stage48x256(pair + (size_t)gm * 12288, tAc, tid);

  bf16x8 wf[8];
  {
    const bf16x8* wp = reinterpret_cast<const bf16x8*>(wfrag_pair);
#pragma unroll
    for (int kt = 0; kt < 8; ++kt) wf[kt] = wp[((gn * 6 + wave) * 8 + kt) * 64 + lane];
  }
  __syncthreads();

  f32x4 acc[3];
#pragma unroll
  for (int mt = 0; mt < 3; ++mt) acc[mt] = (f32x4){0.f, 0.f, 0.f, 0.f};
#pragma unroll
  for (int kt = 0; kt < 8; ++kt) {
#pragma unroll
    for (int mt = 0; mt < 3; ++mt) {
      int row = mt * 16 + (lane & 15);
      int off = (row << 9) + (kt << 6) + ((lane >> 4) << 4);
      off ^= (row & 7) << 4;
      bf16x8 a = *reinterpret_cast<const bf16x8*>(tAc + off);
      acc[mt] = __builtin_amdgcn_mfma_f32_16x16x32_bf16(a, wf[kt], acc[mt], 0, 0, 0);
    }
  }

  int col = gn * 96 + wave * 16 + (lane & 15);
  float bias = biascat[col];
  int jb = (lane >> 4) * 4;
#pragma unroll
  for (int mt = 0; mt < 3; ++mt) {
#pragma unroll
    for (int rr = 0; rr < 4; ++rr) {
      int j = mt * 16 + jb + rr;
      proj[(size_t)(gm * 48 + j) * 768 + col] = acc[mt][rr] + bias;
    }
  }
}

// ---------------------------------------------------------------------------
// Fused main: one block per (b,i,k) slice; 4608 blocks.  Occupancy-first:
// VGPR-light (weights per-kt from L2, no reg prefetch, transient q/v loads),
// LDS union (j-major sqS[48][100] overwrites tAc after GEMM) -> 27.1 KB.
// j-major sqS makes scores phase pure b128 LDS reads (sq/sk as float4).
// Phases: stage -> GEMM -> epilogue(sqS) -> scores -> softmax -> PV.
// XCD swizzle: same-(b,i) slices share an XCD for q/v L2 reuse.
// launch_bounds is a FLOOR: if alloc lands <=64 VGPR, HW gives 5 blocks/CU.
// ---------------------------------------------------------------------------
__global__ __launch_bounds__(384, 6)
void e2e_fused(const float* __restrict__ mask, const float* __restrict__ trip,
               const float* __restrict__ proj, const unsigned short* __restrict__ wfragm,
               const float* __restrict__ biasm, float* __restrict__ out) {
  __shared__ __align__(16) char smem[48 * 256 * 2];  // tAc, later sqS[48][100]
  __shared__ float khl[256];
  __shared__ float pbuf[8][48];
  char* tAc = smem;
  float* sqS = reinterpret_cast<float*>(smem);  // [48][SQS_LD], 19200 B <= 24576

  int tid = threadIdx.x;
  int lane = tid & 63;
  int wave = tid >> 6;

  int bid = blockIdx.x;
  int s = (bid & 7) * 576 + (bid >> 3);  // slice = (b*48+i)*48 + k
  int g = s / 48;                        // (b*48+i)
  int k = s % 48;
  int b = g / 48;
  int rowbase = g * 48;

  stage48x256(trip + (size_t)s * 12288, tAc, tid);
  if (tid < 256) khl[tid] = proj[(size_t)s * 768 + 256 + tid];
  __syncthreads();  // [1] tile staged

  // GEMM: sq|sk|sv = tile @ [Wsq|Wsk|Wsv]; wave = 16-col n-tile
  const bf16x8* wp = reinterpret_cast<const bf16x8*>(wfragm);
  f32x4 acc[3];
#pragma unroll
  for (int mt = 0; mt < 3; ++mt) acc[mt] = (f32x4){0.f, 0.f, 0.f, 0.f};
#pragma unroll
  for (int kt = 0; kt < 8; ++kt) {
    bf16x8 w = wp[(wave * 8 + kt) * 64 + lane];  // L2-hot, 16B/lane
#pragma unroll
    for (int mt = 0; mt < 3; ++mt) {
      int row = mt * 16 + (lane & 15);
      int off = (row << 9) + (kt << 6) + ((lane >> 4) << 4);
      off ^= (row & 7) << 4;
      bf16x8 a = *reinterpret_cast<const bf16x8*>(tAc + off);
      acc[mt] = __builtin_amdgcn_mfma_f32_16x16x32_bf16(a, w, acc[mt], 0, 0, 0);
    }
  }
  __syncthreads();  // [2] all tAc reads done; smem may be rewritten as sqS

  // epilogue: sqS[j][n] = acc + bias  (n: 0-31 sq, 32-63 sk, 64-95 sv)
  // lanes 0-15 vs 16-31 hit disjoint bank halves (row stride 400B -> +16)
  {
    int n = wave * 16 + (lane & 15);
    float bias = biasm[n];
    int jb = (lane >> 4) * 4;
#pragma unroll
    for (int mt = 0; mt < 3; ++mt) {
#pragma unroll
      for (int rr = 0; rr < 4; ++rr)
        sqS[(mt * 16 + jb + rr) * SQS_LD + n] = acc[mt][rr] + bias;
    }
  }
  __syncthreads();  // [3] sqS ready

  // scores: thread (h = tid/48, j = tid%48); all LDS reads are float4 (b128)
  {
    int j = tid % 48, h = tid / 48;
    const float4* q4 = reinterpret_cast<const float4*>(proj + (size_t)(rowbase + j) * 768 + h * 32);
    const float4* sq4 = reinterpret_cast<const float4*>(sqS + j * SQS_LD);
    const float4* kh4 = reinterpret_cast<const float4*>(khl + h * 32);
    float sc = 0.f;
#pragma unroll
    for (int d4 = 0; d4 < 8; ++d4) {
      float4 q = q4[d4];
      float4 sq = sq4[d4];
      float4 sk = sq4[8 + d4];
      float4 kh = kh4[d4];
      sc += (q.x + sq.x) * (kh.x + sk.x);
      sc += (q.y + sq.y) * (kh.y + sk.y);
      sc += (q.z + sq.z) * (kh.z + sk.z);
      sc += (q.w + sq.w) * (kh.w + sk.w);
    }
    pbuf[h][j] = sc * 0.17677669529663687f + mask[b * 2304 + k * 48 + j];  // 1/sqrt(32)
  }
  __syncthreads();  // [4] scores ready

  // softmax over j per head: waves 0..5 take rows wave, wave+6
  for (int h = wave; h < 8; h += 6) {
    float x = (lane < 48) ? pbuf[h][lane] : -INFINITY;
    float m = x;
#pragma unroll
    for (int off = 32; off; off >>= 1) m = fmaxf(m, __shfl_xor(m, off));
    float e = (lane < 48) ? __expf(x - m) : 0.f;
    float sum = e;
#pragma unroll
    for (int off = 32; off; off >>= 1) sum += __shfl_xor(sum, off);
    if (lane < 48) pbuf[h][lane] = e / sum;
  }
  __syncthreads();  // [5] probs ready

  // PV: 256 threads = (h,d); v rows transient from L2 (1KB contiguous per j);
  // sqS[j][64+d] lane-contiguous + broadcast across half-waves.
  if (tid < 256) {
    int h = tid >> 5, d = tid & 31;
    const float* vbase = proj + (size_t)rowbase * 768 + 512 + tid;
    float a = 0.f;
#pragma unroll 8
    for (int j = 0; j < 48; ++j)
      a += pbuf[h][j] * (vbase[(size_t)j * 768] + sqS[j * SQS_LD + 64 + d]);
    out[(size_t)s * 256 + tid] = a;
  }
}

// ---------------------------------------------------------------------------
extern "C" void kernel_launch(void* const* d_in, const int* in_sizes, int n_in,
                              void* d_out, int out_size, void* d_ws, size_t ws_size,
                              hipStream_t stream) {
  const float* mask = (const float*)d_in[0];
  const float* pair = (const float*)d_in[1];
  const float* trip = (const float*)d_in[2];
  const float* Wq = (const float*)d_in[3];
  const float* bq = (const float*)d_in[4];
  const float* Wk = (const float*)d_in[5];
  const float* bk = (const float*)d_in[6];
  const float* Wv = (const float*)d_in[7];
  const float* bv = (const float*)d_in[8];
  const float* Wsq = (const float*)d_in[9];
  const float* bsq = (const float*)d_in[10];
  const float* Wsk = (const float*)d_in[11];
  const float* bsk = (const float*)d_in[12];
  const float* Wsv = (const float*)d_in[13];
  const float* bsv = (const float*)d_in[14];

  char* ws = (char*)d_ws;
  float* proj = (float*)ws;                                               // 14,155,776 B
  unsigned short* wfrag_pair = (unsigned short*)(ws + 14155776);          // 393,216 B
  unsigned short* wfrag_main = (unsigned short*)(ws + 14155776 + 393216); // 49,152 B
  float* biascat = (float*)(ws + 14155776 + 393216 + 49152);              // 3,072 B
  float* biasm = (float*)(ws + 14155776 + 393216 + 49152 + 3072);        // 384 B

  pack_kernel<<<867, 256, 0, stream>>>(Wq, Wk, Wv, bq, bk, bv, Wsq, Wsk, Wsv,
                                       bsq, bsk, bsv,
                                       wfrag_pair, wfrag_main, biascat, biasm);
  pair_proj_kernel<<<768, 384, 0, stream>>>(pair, wfrag_pair, biascat, proj);
  e2e_fused<<<4608, 384, 0, stream>>>(mask, trip, proj, wfrag_main, biasm,
                                      (float*)d_out);
}